// Round 2
// baseline (415.536 us; speedup 1.0000x reference)
//
#include <hip/hip_runtime.h>
#include <math.h>

#define Bq 32
#define Sq 2048
#define Dq 1024
#define Tq 8
#define NTILE 64          // S-tiles for summary stage A
#define TROWS 32          // rows per tile (NTILE * TROWS == Sq)

// ---------------------------------------------------------------------------
// Kernel 1: scores[b,s] = dot(qry[b,:], ctx[b,s,:]) + log(mask[b,s])
// Grid: (S/16, B), block 256 (4 waves). Each wave computes 4 rows.
// Lane l reads float4 index (l + 64k), k=0..3 -> covers D=1024 floats.
// ---------------------------------------------------------------------------
__global__ __launch_bounds__(256) void scores_kernel(
    const float* __restrict__ qry, const float* __restrict__ ctx,
    const float* __restrict__ mask, float* __restrict__ scores)
{
    const int b      = blockIdx.y;
    const int s_base = blockIdx.x * 16;
    const int wave   = threadIdx.x >> 6;
    const int lane   = threadIdx.x & 63;

    const float4* q4 = (const float4*)(qry + (size_t)b * Dq);
    float4 q[4];
#pragma unroll
    for (int k = 0; k < 4; ++k) q[k] = q4[lane + 64 * k];

#pragma unroll
    for (int r = 0; r < 4; ++r) {
        const int s = s_base + wave * 4 + r;
        const float4* c4 = (const float4*)(ctx + ((size_t)b * Sq + s) * Dq);
        float acc = 0.f;
#pragma unroll
        for (int k = 0; k < 4; ++k) {
            float4 c = c4[lane + 64 * k];
            acc += q[k].x * c.x + q[k].y * c.y + q[k].z * c.z + q[k].w * c.w;
        }
#pragma unroll
        for (int off = 32; off >= 1; off >>= 1)
            acc += __shfl_down(acc, off, 64);
        if (lane == 0)
            scores[(size_t)b * Sq + s] = acc + logf(mask[(size_t)b * Sq + s]);
    }
}

// ---------------------------------------------------------------------------
// Kernel 2: softmax over S per row, then alphas = min(parent_alphas, softmax).
// Grid: (B), block 256. Each thread owns 8 s-positions.
// ---------------------------------------------------------------------------
__global__ __launch_bounds__(256) void softmax_min_kernel(
    const float* __restrict__ scores, const float* __restrict__ prevatts,
    const int* __restrict__ parent_ptr, float* __restrict__ alphas)
{
    const int b = blockIdx.x;
    const int t = threadIdx.x;
    __shared__ float redmax[4];
    __shared__ float redsum[4];

    const float* srow = scores + (size_t)b * Sq;
    float vals[8];
    float m = -INFINITY;
#pragma unroll
    for (int i = 0; i < 8; ++i) {
        vals[i] = srow[t + 256 * i];
        m = fmaxf(m, vals[i]);
    }
#pragma unroll
    for (int off = 32; off >= 1; off >>= 1)
        m = fmaxf(m, __shfl_down(m, off, 64));
    if ((t & 63) == 0) redmax[t >> 6] = m;
    __syncthreads();
    m = fmaxf(fmaxf(redmax[0], redmax[1]), fmaxf(redmax[2], redmax[3]));

    float sum = 0.f;
#pragma unroll
    for (int i = 0; i < 8; ++i) {
        vals[i] = expf(vals[i] - m);
        sum += vals[i];
    }
#pragma unroll
    for (int off = 32; off >= 1; off >>= 1)
        sum += __shfl_down(sum, off, 64);
    if ((t & 63) == 0) redsum[t >> 6] = sum;
    __syncthreads();
    sum = redsum[0] + redsum[1] + redsum[2] + redsum[3];
    const float inv = 1.0f / sum;

    const float* par = prevatts + ((size_t)b * Tq + parent_ptr[b]) * Sq;
#pragma unroll
    for (int i = 0; i < 8; ++i) {
        const int s = t + 256 * i;
        alphas[(size_t)b * Sq + s] = fminf(par[s], vals[i] * inv);
    }
}

// ---------------------------------------------------------------------------
// Kernel 3a: partial[b, tile, d] = sum_{s in tile} alphas[b,s] * ctx[b,s,d]
// Grid: (NTILE, B) = (64, 32) = 2048 blocks, block 256 (8 blocks/CU).
// Thread t owns float4 column t. Fully-unrolled 32-iter loop -> high MLP.
// No atomics, no zero-init dependency.
// ---------------------------------------------------------------------------
__global__ __launch_bounds__(256) void summary_partial_kernel(
    const float* __restrict__ ctx, const float* __restrict__ alphas,
    float* __restrict__ partial)
{
    const int b      = blockIdx.y;
    const int tile   = blockIdx.x;
    const int s_base = tile * TROWS;
    const int t      = threadIdx.x;

    __shared__ float la[TROWS];
    if (t < TROWS) la[t] = alphas[(size_t)b * Sq + s_base + t];
    __syncthreads();

    const float4* c4 = (const float4*)(ctx + ((size_t)b * Sq + s_base) * Dq);
    float4 acc = make_float4(0.f, 0.f, 0.f, 0.f);
#pragma unroll
    for (int s = 0; s < TROWS; ++s) {
        const float a = la[s];
        float4 c = c4[(size_t)s * (Dq / 4) + t];
        acc.x += a * c.x;
        acc.y += a * c.y;
        acc.z += a * c.z;
        acc.w += a * c.w;
    }
    float4* p4 = (float4*)(partial + (((size_t)b * NTILE) + tile) * Dq);
    p4[t] = acc;
}

// ---------------------------------------------------------------------------
// Kernel 3b: summary[b,d] = sum_tile partial[b,tile,d]
// 8192 float4 outputs; grid 32 blocks x 256 threads.
// ---------------------------------------------------------------------------
__global__ __launch_bounds__(256) void summary_reduce_kernel(
    const float* __restrict__ partial, float* __restrict__ summary)
{
    const int idx = blockIdx.x * 256 + threadIdx.x;   // float4 index, 0..8191
    const int b   = idx >> 8;                         // / 256
    const int dq  = idx & 255;

    const float4* p4 = (const float4*)(partial + (size_t)b * NTILE * Dq);
    float4 acc = make_float4(0.f, 0.f, 0.f, 0.f);
#pragma unroll 8
    for (int tile = 0; tile < NTILE; ++tile) {
        float4 v = p4[(size_t)tile * (Dq / 4) + dq];
        acc.x += v.x;
        acc.y += v.y;
        acc.z += v.z;
        acc.w += v.w;
    }
    ((float4*)summary)[idx] = acc;
}

extern "C" void kernel_launch(void* const* d_in, const int* in_sizes, int n_in,
                              void* d_out, int out_size, void* d_ws, size_t ws_size,
                              hipStream_t stream)
{
    const float* qry        = (const float*)d_in[0];
    const float* ctx        = (const float*)d_in[1];
    const float* mask       = (const float*)d_in[2];
    const float* prevatts   = (const float*)d_in[3];
    const int*   parent_ptr = (const int*)d_in[4];

    float* out     = (float*)d_out;
    float* alphas  = out;                     // B*S = 65536
    float* summary = out + Bq * Sq;           // B*D = 32768
    float* scores  = out + Bq * Sq + Bq * Dq; // B*S = 65536

    float* partial = (float*)d_ws;            // B*NTILE*D floats = 8 MB

    scores_kernel<<<dim3(Sq / 16, Bq), 256, 0, stream>>>(qry, ctx, mask, scores);
    softmax_min_kernel<<<Bq, 256, 0, stream>>>(scores, prevatts, parent_ptr, alphas);
    summary_partial_kernel<<<dim3(NTILE, Bq), 256, 0, stream>>>(ctx, alphas, partial);
    summary_reduce_kernel<<<(Bq * Dq / 4) / 256, 256, 0, stream>>>(partial, summary);
}

// Round 3
// 379.082 us; speedup vs baseline: 1.0962x; 1.0962x over previous
//
#include <hip/hip_runtime.h>
#include <math.h>

#define Bq 32
#define Sq 2048
#define Dq 1024
#define Tq 8
#define TILE 16            // S-rows per block in kernel A
#define NT (Sq / TILE)     // 128 tiles per batch row

// ---------------------------------------------------------------------------
// Kernel A: for each 16-row tile of (b):
//   scores[b,s] = dot(qry[b,:], ctx[b,s,:]) + log(mask[b,s])   (written out)
//   partial[b,tile,:] = sum_{s in tile} exp(scores[s] - m_tile) * ctx[b,s,:]
// ctx tile is held in registers between the dot and the weighted sum, so ctx
// is read from HBM exactly ONCE for the whole problem.
// Grid (NT, B) = (128, 32), block 256 (4 waves, 4 rows/wave).
// ---------------------------------------------------------------------------
__global__ __launch_bounds__(256) void fused_scores_partial_kernel(
    const float* __restrict__ qry, const float* __restrict__ ctx,
    const float* __restrict__ mask, float* __restrict__ scores,
    float4* __restrict__ partial)
{
    const int b    = blockIdx.y;
    const int tile = blockIdx.x;
    const int s0   = tile * TILE;
    const int wave = threadIdx.x >> 6;
    const int lane = threadIdx.x & 63;

    __shared__ float  tsc[TILE];
    __shared__ float4 buf[4 * 256];    // 16 KB wave-partial exchange

    const float4* q4 = (const float4*)(qry + (size_t)b * Dq);
    float4 q[4];
#pragma unroll
    for (int k = 0; k < 4; ++k) q[k] = q4[lane + 64 * k];

    // Load the whole 4-row slice for this wave (16 float4/lane, kept live).
    float4 c[4][4];
#pragma unroll
    for (int r = 0; r < 4; ++r) {
        const int s = s0 + wave * 4 + r;
        const float4* c4 = (const float4*)(ctx + ((size_t)b * Sq + s) * Dq);
#pragma unroll
        for (int k = 0; k < 4; ++k) c[r][k] = c4[lane + 64 * k];
    }

    float sc[4];
#pragma unroll
    for (int r = 0; r < 4; ++r) {
        float acc = 0.f;
#pragma unroll
        for (int k = 0; k < 4; ++k)
            acc += q[k].x * c[r][k].x + q[k].y * c[r][k].y
                 + q[k].z * c[r][k].z + q[k].w * c[r][k].w;
#pragma unroll
        for (int off = 1; off < 64; off <<= 1)     // butterfly: all lanes get sum
            acc += __shfl_xor(acc, off, 64);
        const int s = s0 + wave * 4 + r;
        acc += logf(mask[(size_t)b * Sq + s]);
        sc[r] = acc;
        if (lane == 0) {
            scores[(size_t)b * Sq + s] = acc;
            tsc[wave * 4 + r] = acc;
        }
    }
    __syncthreads();

    float m = -INFINITY;
#pragma unroll
    for (int i = 0; i < TILE; ++i) m = fmaxf(m, tsc[i]);

    float4 pacc[4];
#pragma unroll
    for (int k = 0; k < 4; ++k) pacc[k] = make_float4(0.f, 0.f, 0.f, 0.f);
#pragma unroll
    for (int r = 0; r < 4; ++r) {
        const float e = expf(sc[r] - m);
#pragma unroll
        for (int k = 0; k < 4; ++k) {
            pacc[k].x += e * c[r][k].x;
            pacc[k].y += e * c[r][k].y;
            pacc[k].z += e * c[r][k].z;
            pacc[k].w += e * c[r][k].w;
        }
    }
#pragma unroll
    for (int k = 0; k < 4; ++k) buf[wave * 256 + lane + 64 * k] = pacc[k];
    __syncthreads();

    const int t = threadIdx.x;
    float4 s0v = buf[t], s1v = buf[256 + t], s2v = buf[512 + t], s3v = buf[768 + t];
    float4 sum;
    sum.x = (s0v.x + s1v.x) + (s2v.x + s3v.x);
    sum.y = (s0v.y + s1v.y) + (s2v.y + s3v.y);
    sum.z = (s0v.z + s1v.z) + (s2v.z + s3v.z);
    sum.w = (s0v.w + s1v.w) + (s2v.w + s3v.w);
    partial[((size_t)b * NT + tile) * 256 + t] = sum;
}

// ---------------------------------------------------------------------------
// Kernel B: one block per batch row.
//   1. softmax over scores (recomputed from A's bit-exact output)
//   2. alphas = min(parent, softmax); compact clipped rows (alpha > parent)
//   3. summary = sum_tile exp(m_tile - m)/Z * partial[tile]  -  sparse corr.
// Expected #clipped rows per b is ~1 (sum of alphas = 1, p ~ U[0,1]); exact
// for any data (capacity Sq).
// ---------------------------------------------------------------------------
__global__ __launch_bounds__(256) void finalize_kernel(
    const float* __restrict__ ctx, const float* __restrict__ scores,
    const float* __restrict__ prevatts, const int* __restrict__ parent_ptr,
    const float4* __restrict__ partial, float* __restrict__ alphas,
    float4* __restrict__ summary)
{
    const int b = blockIdx.x;
    const int t = threadIdx.x;

    __shared__ float ssc[Sq];       // 8 KB: staged scores row
    __shared__ float redA[4], redB[4];
    __shared__ float ftile[NT];     // per-tile rescale factor
    __shared__ int   sidx[Sq];      // clipped-row indices (worst case all)
    __shared__ float sg[Sq];        // clipped-row excess alpha-p
    __shared__ int   scount;

    if (t == 0) scount = 0;

    const float* srow = scores + (size_t)b * Sq;
    float vals[8];
    float m = -INFINITY;
#pragma unroll
    for (int i = 0; i < 8; ++i) {
        float v = srow[t + 256 * i];
        ssc[t + 256 * i] = v;
        vals[i] = v;
        m = fmaxf(m, v);
    }
#pragma unroll
    for (int off = 1; off < 64; off <<= 1)
        m = fmaxf(m, __shfl_xor(m, off, 64));
    if ((t & 63) == 0) redA[t >> 6] = m;
    __syncthreads();                       // also covers ssc writes + scount init
    m = fmaxf(fmaxf(redA[0], redA[1]), fmaxf(redA[2], redA[3]));

    float sum = 0.f;
#pragma unroll
    for (int i = 0; i < 8; ++i) {
        vals[i] = expf(vals[i] - m);
        sum += vals[i];
    }
#pragma unroll
    for (int off = 1; off < 64; off <<= 1)
        sum += __shfl_xor(sum, off, 64);
    if ((t & 63) == 0) redB[t >> 6] = sum;
    __syncthreads();
    sum = (redB[0] + redB[1]) + (redB[2] + redB[3]);
    const float invZ = 1.0f / sum;

    // per-tile rescale factor: exp(m_tile - m) / Z  (m_tile from bit-exact ssc)
    if (t < NT) {
        float tm = -INFINITY;
#pragma unroll
        for (int i = 0; i < TILE; ++i) tm = fmaxf(tm, ssc[t * TILE + i]);
        ftile[t] = expf(tm - m) * invZ;
    }

    // alphas + compaction of clipped rows
    const float* par = prevatts + ((size_t)b * Tq + parent_ptr[b]) * Sq;
#pragma unroll
    for (int i = 0; i < 8; ++i) {
        const int s = t + 256 * i;
        const float a = vals[i] * invZ;
        const float p = par[s];
        alphas[(size_t)b * Sq + s] = fminf(p, a);
        const float g = a - p;
        if (g > 0.f) {
            int pos = atomicAdd(&scount, 1);
            sidx[pos] = s;
            sg[pos]  = g;
        }
    }
    __syncthreads();                       // covers ftile, sidx/sg, scount

    // summary = sum_tile ftile * partial[tile] - sum_clipped g * ctx_row
    const float4* pp = partial + (size_t)b * NT * 256;
    float4 acc = make_float4(0.f, 0.f, 0.f, 0.f);
#pragma unroll 8
    for (int tile = 0; tile < NT; ++tile) {
        const float f = ftile[tile];
        float4 v = pp[(size_t)tile * 256 + t];
        acc.x += f * v.x;
        acc.y += f * v.y;
        acc.z += f * v.z;
        acc.w += f * v.w;
    }
    const int cnt = scount;
    const float4* cb = (const float4*)(ctx + (size_t)b * Sq * Dq);
    for (int i = 0; i < cnt; ++i) {
        const int   s = sidx[i];
        const float g = sg[i];
        float4 v = cb[(size_t)s * 256 + t];
        acc.x -= g * v.x;
        acc.y -= g * v.y;
        acc.z -= g * v.z;
        acc.w -= g * v.w;
    }
    summary[b * 256 + t] = acc;
}

extern "C" void kernel_launch(void* const* d_in, const int* in_sizes, int n_in,
                              void* d_out, int out_size, void* d_ws, size_t ws_size,
                              hipStream_t stream)
{
    const float* qry        = (const float*)d_in[0];
    const float* ctx        = (const float*)d_in[1];
    const float* mask       = (const float*)d_in[2];
    const float* prevatts   = (const float*)d_in[3];
    const int*   parent_ptr = (const int*)d_in[4];

    float* out     = (float*)d_out;
    float* alphas  = out;                      // B*S = 65536
    float* summary = out + Bq * Sq;            // B*D = 32768
    float* scores  = out + Bq * Sq + Bq * Dq;  // B*S = 65536

    float4* partial = (float4*)d_ws;           // B*NT*D floats = 16 MB

    fused_scores_partial_kernel<<<dim3(NT, Bq), 256, 0, stream>>>(
        qry, ctx, mask, scores, partial);
    finalize_kernel<<<Bq, 256, 0, stream>>>(
        ctx, scores, prevatts, parent_ptr, partial, alphas, (float4*)summary);
}

// Round 4
// 371.213 us; speedup vs baseline: 1.1194x; 1.0212x over previous
//
#include <hip/hip_runtime.h>
#include <math.h>

#define Bq 32
#define Sq 2048
#define Dq 1024
#define Tq 8
#define TILE 32            // S-rows per block in kernel A
#define NT (Sq / TILE)     // 64 tiles per batch row

// ---------------------------------------------------------------------------
// Kernel A: for each 32-row tile of (b):
//   scores[b,s] = dot(qry[b,:], ctx[b,s,:]) + log(mask[b,s])   (written out)
//   partial[b,tile,:] = sum_{s in tile} exp(scores[s] - m_tile) * ctx[b,s,:]
// Each wave owns 8 rows, processed as two 4-row register-resident chunks with
// online max-rescale; cross-wave combine rescales by exp(m_wave - m_tile).
// ctx is read from HBM exactly once for the whole problem.
// Grid (NT, B) = (64, 32), block 256 (4 waves).
// ---------------------------------------------------------------------------
__global__ __launch_bounds__(256) void fused_scores_partial_kernel(
    const float* __restrict__ qry, const float* __restrict__ ctx,
    const float* __restrict__ mask, float* __restrict__ scores,
    float4* __restrict__ partial)
{
    const int b    = blockIdx.y;
    const int tile = blockIdx.x;
    const int s0   = tile * TILE;
    const int wave = threadIdx.x >> 6;
    const int lane = threadIdx.x & 63;

    __shared__ float  wmax[4];
    __shared__ float4 buf[4 * 256];    // 16 KB wave-partial exchange

    const float4* q4 = (const float4*)(qry + (size_t)b * Dq);
    float4 q[4];
#pragma unroll
    for (int k = 0; k < 4; ++k) q[k] = q4[lane + 64 * k];

    float4 pacc[4];
#pragma unroll
    for (int k = 0; k < 4; ++k) pacc[k] = make_float4(0.f, 0.f, 0.f, 0.f);
    float mw = -INFINITY;

#pragma unroll
    for (int p = 0; p < 2; ++p) {
        const int sbase = s0 + wave * 8 + p * 4;

        float4 c[4][4];
#pragma unroll
        for (int r = 0; r < 4; ++r) {
            const float4* c4 = (const float4*)(ctx + ((size_t)b * Sq + sbase + r) * Dq);
#pragma unroll
            for (int k = 0; k < 4; ++k) c[r][k] = c4[lane + 64 * k];
        }

        float sc[4];
#pragma unroll
        for (int r = 0; r < 4; ++r) {
            float acc = 0.f;
#pragma unroll
            for (int k = 0; k < 4; ++k)
                acc += q[k].x * c[r][k].x + q[k].y * c[r][k].y
                     + q[k].z * c[r][k].z + q[k].w * c[r][k].w;
#pragma unroll
            for (int off = 1; off < 64; off <<= 1)   // butterfly: all lanes get sum
                acc += __shfl_xor(acc, off, 64);
            acc += logf(mask[(size_t)b * Sq + sbase + r]);
            sc[r] = acc;
            if (lane == 0) scores[(size_t)b * Sq + sbase + r] = acc;
        }

        float mc = fmaxf(fmaxf(sc[0], sc[1]), fmaxf(sc[2], sc[3]));
        const float mnew = fmaxf(mw, mc);
        const float scale = (p == 0) ? 0.f : expf(mw - mnew); // p==0: pacc is 0
        mw = mnew;
#pragma unroll
        for (int k = 0; k < 4; ++k) {
            pacc[k].x *= scale; pacc[k].y *= scale;
            pacc[k].z *= scale; pacc[k].w *= scale;
        }
#pragma unroll
        for (int r = 0; r < 4; ++r) {
            const float e = expf(sc[r] - mw);
#pragma unroll
            for (int k = 0; k < 4; ++k) {
                pacc[k].x += e * c[r][k].x;
                pacc[k].y += e * c[r][k].y;
                pacc[k].z += e * c[r][k].z;
                pacc[k].w += e * c[r][k].w;
            }
        }
    }

    if (lane == 0) wmax[wave] = mw;
#pragma unroll
    for (int k = 0; k < 4; ++k) buf[wave * 256 + lane + 64 * k] = pacc[k];
    __syncthreads();

    const float mt = fmaxf(fmaxf(wmax[0], wmax[1]), fmaxf(wmax[2], wmax[3]));
    const float f0 = expf(wmax[0] - mt), f1 = expf(wmax[1] - mt);
    const float f2 = expf(wmax[2] - mt), f3 = expf(wmax[3] - mt);

    const int t = threadIdx.x;
    float4 v0 = buf[t], v1 = buf[256 + t], v2 = buf[512 + t], v3 = buf[768 + t];
    float4 sum;
    sum.x = (f0 * v0.x + f1 * v1.x) + (f2 * v2.x + f3 * v3.x);
    sum.y = (f0 * v0.y + f1 * v1.y) + (f2 * v2.y + f3 * v3.y);
    sum.z = (f0 * v0.z + f1 * v1.z) + (f2 * v2.z + f3 * v3.z);
    sum.w = (f0 * v0.w + f1 * v1.w) + (f2 * v2.w + f3 * v3.w);
    partial[((size_t)b * NT + tile) * 256 + t] = sum;
}

// ---------------------------------------------------------------------------
// Kernel B: one block per batch row.
//   1. softmax over scores (recomputed from A's bit-exact output)
//   2. alphas = min(parent, softmax); compact clipped rows (alpha > parent)
//   3. summary = sum_tile exp(m_tile - m)/Z * partial[tile]  -  sparse corr.
// E[#clipped rows] per b is ~1 (sum of alphas = 1, parent ~ U[0,1]); exact
// for any data (capacity Sq).
// ---------------------------------------------------------------------------
__global__ __launch_bounds__(256) void finalize_kernel(
    const float* __restrict__ ctx, const float* __restrict__ scores,
    const float* __restrict__ prevatts, const int* __restrict__ parent_ptr,
    const float4* __restrict__ partial, float* __restrict__ alphas,
    float4* __restrict__ summary)
{
    const int b = blockIdx.x;
    const int t = threadIdx.x;

    __shared__ float ssc[Sq];       // 8 KB: staged scores row
    __shared__ float redA[4], redB[4];
    __shared__ float ftile[NT];     // per-tile rescale factor
    __shared__ int   sidx[Sq];      // clipped-row indices (worst case all)
    __shared__ float sg[Sq];        // clipped-row excess alpha-p
    __shared__ int   scount;

    if (t == 0) scount = 0;

    const float* srow = scores + (size_t)b * Sq;
    float vals[8];
    float m = -INFINITY;
#pragma unroll
    for (int i = 0; i < 8; ++i) {
        float v = srow[t + 256 * i];
        ssc[t + 256 * i] = v;
        vals[i] = v;
        m = fmaxf(m, v);
    }
#pragma unroll
    for (int off = 1; off < 64; off <<= 1)
        m = fmaxf(m, __shfl_xor(m, off, 64));
    if ((t & 63) == 0) redA[t >> 6] = m;
    __syncthreads();                       // also covers ssc writes + scount init
    m = fmaxf(fmaxf(redA[0], redA[1]), fmaxf(redA[2], redA[3]));

    float sum = 0.f;
#pragma unroll
    for (int i = 0; i < 8; ++i) {
        vals[i] = expf(vals[i] - m);
        sum += vals[i];
    }
#pragma unroll
    for (int off = 1; off < 64; off <<= 1)
        sum += __shfl_xor(sum, off, 64);
    if ((t & 63) == 0) redB[t >> 6] = sum;
    __syncthreads();
    sum = (redB[0] + redB[1]) + (redB[2] + redB[3]);
    const float invZ = 1.0f / sum;

    // per-tile rescale factor: exp(m_tile - m) / Z  (m_tile from bit-exact ssc)
    if (t < NT) {
        float tm = -INFINITY;
#pragma unroll
        for (int i = 0; i < TILE; ++i) tm = fmaxf(tm, ssc[t * TILE + i]);
        ftile[t] = expf(tm - m) * invZ;
    }

    // alphas + compaction of clipped rows
    const float* par = prevatts + ((size_t)b * Tq + parent_ptr[b]) * Sq;
#pragma unroll
    for (int i = 0; i < 8; ++i) {
        const int s = t + 256 * i;
        const float a = vals[i] * invZ;
        const float p = par[s];
        alphas[(size_t)b * Sq + s] = fminf(p, a);
        const float g = a - p;
        if (g > 0.f) {
            int pos = atomicAdd(&scount, 1);
            sidx[pos] = s;
            sg[pos]  = g;
        }
    }
    __syncthreads();                       // covers ftile, sidx/sg, scount

    // summary = sum_tile ftile * partial[tile] - sum_clipped g * ctx_row
    const float4* pp = partial + (size_t)b * NT * 256;
    float4 acc = make_float4(0.f, 0.f, 0.f, 0.f);
#pragma unroll 8
    for (int tile = 0; tile < NT; ++tile) {
        const float f = ftile[tile];
        float4 v = pp[(size_t)tile * 256 + t];
        acc.x += f * v.x;
        acc.y += f * v.y;
        acc.z += f * v.z;
        acc.w += f * v.w;
    }
    const int cnt = scount;
    const float4* cb = (const float4*)(ctx + (size_t)b * Sq * Dq);
    for (int i = 0; i < cnt; ++i) {
        const int   s = sidx[i];
        const float g = sg[i];
        float4 v = cb[(size_t)s * 256 + t];
        acc.x -= g * v.x;
        acc.y -= g * v.y;
        acc.z -= g * v.z;
        acc.w -= g * v.w;
    }
    summary[b * 256 + t] = acc;
}

extern "C" void kernel_launch(void* const* d_in, const int* in_sizes, int n_in,
                              void* d_out, int out_size, void* d_ws, size_t ws_size,
                              hipStream_t stream)
{
    const float* qry        = (const float*)d_in[0];
    const float* ctx        = (const float*)d_in[1];
    const float* mask       = (const float*)d_in[2];
    const float* prevatts   = (const float*)d_in[3];
    const int*   parent_ptr = (const int*)d_in[4];

    float* out     = (float*)d_out;
    float* alphas  = out;                      // B*S = 65536
    float* summary = out + Bq * Sq;            // B*D = 32768
    float* scores  = out + Bq * Sq + Bq * Dq;  // B*S = 65536

    float4* partial = (float4*)d_ws;           // B*NT*D floats = 8 MB

    fused_scores_partial_kernel<<<dim3(NT, Bq), 256, 0, stream>>>(
        qry, ctx, mask, scores, partial);
    finalize_kernel<<<Bq, 256, 0, stream>>>(
        ctx, scores, prevatts, parent_ptr, partial, alphas, (float4*)summary);
}